// Round 20
// baseline (143.491 us; speedup 1.0000x reference)
//
#include <hip/hip_runtime.h>
#include <math.h>

// x: [32,3,512,512] f32.
// Single fused kernel. Stage 1 = r15 verbatim (best measured: ~26.5us).
// Fused stage 2 with CORRECTED completion protocol (r19 bug: atomicAdd
// was issued BEFORE __syncthreads, so counters could advance before
// sibling waves wrote their partials -> race. Correct order per the
// threadFenceReduction pattern: writes -> fence(all) -> barrier -> atomic).
//  - per-(b,c) counter: the 11th finishing block's wave 0 reduces that
//    channel's 44 double2 partials (fixed-order shfl tree -> deterministic).
//  - per-batch counter: the wave finishing the 3rd channel runs the
//    6->32(relu)->64 MLP with __shfl broadcast, writes out[b*64+lane].
// Sync: device-scope atomicAdd + __threadfence. cnts zeroed per call via
// hipMemsetAsync (graph-safe).

__global__ __launch_bounds__(256) void sobel_pool_fused(
    const float* __restrict__ x, double* __restrict__ parts,
    float* __restrict__ festsF, int* __restrict__ cnts,
    const float* __restrict__ w1, const float* __restrict__ b1,
    const float* __restrict__ w2, const float* __restrict__ b2,
    float* __restrict__ out) {
  const int tid = threadIdx.x;
  const int lane = tid & 63;
  const int w = tid >> 6;
  const int bc = blockIdx.y;                 // 0..95
  const int chunk = blockIdx.x * 4 + w;      // 0..43 (43 = dummy)
  const int row0 = chunk * 12;

  const float* __restrict__ xb = x + (size_t)bc * (512 * 512) + lane * 8;

  auto load8 = [&](int r, float* o) {
    if ((unsigned)r < 512u) {                // wave-uniform branch
      const float* p = xb + (size_t)r * 512;
      float4 u = *(const float4*)(p);
      float4 v = *(const float4*)(p + 4);
      o[0] = u.x; o[1] = u.y; o[2] = u.z; o[3] = u.w;
      o[4] = v.x; o[5] = v.y; o[6] = v.z; o[7] = v.w;
    } else {
#pragma unroll
      for (int k = 0; k < 8; ++k) o[k] = 0.f;
    }
  };

  float S[8], X[8];
  {
    float t0[8], t1[8];
    load8(row0 - 2, t0);
    load8(row0 - 1, t1);
#pragma unroll
    for (int k = 0; k < 8; ++k) { S[k] = t0[k] + t1[k]; X[k] = t1[k]; }
  }

  auto magstep = [&](int rm, float* mg) {
    float xn[8], S2[8], a[8], b[8];
    load8(rm + 1, xn);
#pragma unroll
    for (int k = 0; k < 8; ++k) S2[k] = X[k] + xn[k];
#pragma unroll
    for (int k = 0; k < 8; ++k) { a[k] = S[k] + S2[k]; b[k] = S[k] - S2[k]; }
    float aL = __shfl_up(a[7], 1), aR = __shfl_down(a[0], 1);
    float bL = __shfl_up(b[7], 1), bR = __shfl_down(b[0], 1);
    if (lane == 0)  { aL = 0.f; bL = 0.f; }   // image col -1 = 0
    if (lane == 63) { aR = 0.f; bR = 0.f; }   // image col 512 = 0
    const float rmask = ((unsigned)rm < 512u) ? 1.f : 0.f;
#pragma unroll
    for (int j = 0; j < 8; ++j) {
      float am = j ? a[j - 1] : aL;
      float ap = (j < 7) ? a[j + 1] : aR;
      float bm = j ? b[j - 1] : bL;
      float bp = (j < 7) ? b[j + 1] : bR;
      float gx = am - ap;                      // horiz [1,0,-1]
      float gy = fmaf(2.f, b[j], bm + bp);     // horiz [1,2,1]
      float m2 = fmaf(gx, gx, 1e-6f);
      m2 = fmaf(gy, gy, m2);
      mg[j] = __builtin_amdgcn_sqrtf(m2) * rmask;
    }
#pragma unroll
    for (int k = 0; k < 8; ++k) { S[k] = S2[k]; X[k] = xn[k]; }
  };

  float MM[8], MC[8], MP[8];
  magstep(row0 - 1, MM);
  magstep(row0, MC);

  float s = 0.f, ss = 0.f;
#pragma unroll
  for (int i = 0; i < 12; ++i) {
    magstep(row0 + 1 + i, MP);               // mag[r+1]
    if ((unsigned)(row0 + i) < 512u) {       // wave-uniform: real output row
      float cs[8];
#pragma unroll
      for (int k = 0; k < 8; ++k) cs[k] = (MM[k] + MP[k]) + MC[k];
      float csL = __shfl_up(cs[7], 1), csR = __shfl_down(cs[0], 1);
      if (lane == 0) csL = 0.f;
      if (lane == 63) csR = 0.f;
#pragma unroll
      for (int j = 0; j < 8; ++j) {
        float cm = j ? cs[j - 1] : csL;
        float cp = (j < 7) ? cs[j + 1] : csR;
        float t = (cm + cp) + cs[j];
        s += t;
        ss = fmaf(t, t, ss);
      }
    }
#pragma unroll
    for (int k = 0; k < 8; ++k) { MM[k] = MC[k]; MC[k] = MP[k]; }
  }

  // per-wave double reduction; fold deferred /9, /81
  double ds = (double)s * (1.0 / 9.0);
  double dss = (double)ss * (1.0 / 81.0);
  for (int off = 32; off > 0; off >>= 1) {
    ds += __shfl_down(ds, off);
    dss += __shfl_down(dss, off);
  }
  if (lane == 0) {
    size_t idx = ((size_t)bc * 44 + chunk) * 2;
    parts[idx] = ds;
    parts[idx + 1] = dss;
  }

  // ---- fused stage 2: distributed completion (corrected ordering) ----
  __threadfence();           // each thread flushes its own writes (device)
  __syncthreads();           // ALL waves' writes + fences complete ...
  __shared__ int lastBc;
  if (tid == 0)              // ... BEFORE the block announces completion
    lastBc = (atomicAdd(&cnts[bc], 1) == (int)gridDim.x - 1) ? 1 : 0;
  __syncthreads();

  if (lastBc && w == 0) {
    __threadfence();                          // acquire: see all parts[bc]
    const double2* p2 = (const double2*)(parts + (size_t)bc * 88);
    double rs = 0.0, rss = 0.0;
    if (lane < 44) {
      double2 v = p2[lane];
      rs = v.x;
      rss = v.y;
    }
    for (int off = 32; off > 0; off >>= 1) {
      rs += __shfl_down(rs, off);
      rss += __shfl_down(rss, off);
    }
    const int b = bc / 3;
    const int c = bc - 3 * b;
    if (lane == 0) {
      const double N = 262144.0;
      double mean = rs / N;
      double var = (rss - rs * rs / N) / (N - 1.0);
      if (var < 0.0) var = 0.0;
      festsF[b * 6 + 2 * c] = (float)mean;
      festsF[b * 6 + 2 * c + 1] = (float)sqrt(var);
      __threadfence();                        // release festsF (same thread)
    }
    int last = 0;
    if (lane == 0) last = (atomicAdd(&cnts[96 + b], 1) == 2) ? 1 : 0;
    last = __shfl(last, 0);
    if (last) {
      __threadfence();                        // acquire: see all 3 channels
      float f[6];
#pragma unroll
      for (int k = 0; k < 6; ++k) f[k] = festsF[b * 6 + k];
      float h = 0.f;
      if (lane < 32) {
        h = b1[lane];
#pragma unroll
        for (int k = 0; k < 6; ++k) h = fmaf(f[k], w1[lane * 6 + k], h);
        h = h > 0.f ? h : 0.f;
      }
      float acc = b2[lane];
#pragma unroll
      for (int j = 0; j < 32; ++j)
        acc = fmaf(__shfl(h, j), w2[lane * 32 + j], acc);
      out[(size_t)b * 64 + lane] = acc;
    }
  }
}

extern "C" void kernel_launch(void* const* d_in, const int* in_sizes, int n_in,
                              void* d_out, int out_size, void* d_ws, size_t ws_size,
                              hipStream_t stream) {
  const float* x = (const float*)d_in[0];
  const float* w1 = (const float*)d_in[1];
  const float* b1 = (const float*)d_in[2];
  const float* w2 = (const float*)d_in[3];
  const float* b2 = (const float*)d_in[4];
  float* out = (float*)d_out;

  // d_ws layout: parts [0, 67584) | festsF [67584, 68352) | cnts [68352, 68864)
  double* parts = (double*)d_ws;                       // 96*44*2 doubles
  float* festsF = (float*)((char*)d_ws + 67584);       // 96*2 floats
  int* cnts = (int*)((char*)d_ws + 68352);             // 96 + 32 ints

  hipMemsetAsync(cnts, 0, 512, stream);                // graph-safe

  dim3 grid(11, 96);
  sobel_pool_fused<<<grid, 256, 0, stream>>>(x, parts, festsF, cnts,
                                             w1, b1, w2, b2, out);
}

// Round 21
// 30.236 us; speedup vs baseline: 4.7456x; 4.7456x over previous
//
#include <hip/hip_runtime.h>
#include <math.h>

// x: [32,3,512,512] f32.  REVERT to r15 — measured optimum (30.2us wall).
// Stage 1 (~26.5us): register-only row sweep, 8 cols/lane (2 aligned
// float4 loads/row; wave spans 512 cols), Sobel via rolling vertical
// pair-sums, 4 shuffles/mag row + 2/pool row, builtin v_sqrt_f32,
// 12 output rows/wave, 44 chunks/(b,c) (43 real + 1 dummy), 4224 waves.
// Experiment ledger (all regressed vs this): 8-row chunks (r10), dist-4
// prefetch ring (r11, VGPR>128), dist-2 ring (r12), LDS mag-share (r8,
// bank conflicts), LDS x-stage (r7), 4-col shuffle-free (r13/r14),
// 12-col-window shuffle-free (r17), packed fp32 (r18), FAST/SAFE template
// (r16, I-cache), single-kernel fusion (r19 race / r20 codegen collapse).
// Stage 2 (~1us): 32 blocks (one per b); waves 0-2 reduce each channel's
// 44 double2 partials lane-parallel, then 6->32(relu)->64 MLP.
// Grid: (11, 96) x 256  +  (32) x 256.

__global__ __launch_bounds__(256) void sobel_pool_stats(
    const float* __restrict__ x, double* __restrict__ parts) {
  const int tid = threadIdx.x;
  const int lane = tid & 63;
  const int w = tid >> 6;
  const int bc = blockIdx.y;                 // 0..95
  const int chunk = blockIdx.x * 4 + w;      // 0..43 (43 = dummy)
  const int row0 = chunk * 12;

  const float* __restrict__ xb = x + (size_t)bc * (512 * 512) + lane * 8;

  auto load8 = [&](int r, float* o) {
    if ((unsigned)r < 512u) {                // wave-uniform branch
      const float* p = xb + (size_t)r * 512;
      float4 u = *(const float4*)(p);
      float4 v = *(const float4*)(p + 4);
      o[0] = u.x; o[1] = u.y; o[2] = u.z; o[3] = u.w;
      o[4] = v.x; o[5] = v.y; o[6] = v.z; o[7] = v.w;
    } else {
#pragma unroll
      for (int k = 0; k < 8; ++k) o[k] = 0.f;
    }
  };

  float S[8], X[8];
  {
    float t0[8], t1[8];
    load8(row0 - 2, t0);
    load8(row0 - 1, t1);
#pragma unroll
    for (int k = 0; k < 8; ++k) { S[k] = t0[k] + t1[k]; X[k] = t1[k]; }
  }

  // Emit mag row rm (consumes x[rm+1]); advances S,X. mg=0 if rm OOB.
  auto magstep = [&](int rm, float* mg) {
    float xn[8], S2[8], a[8], b[8];
    load8(rm + 1, xn);
#pragma unroll
    for (int k = 0; k < 8; ++k) S2[k] = X[k] + xn[k];
#pragma unroll
    for (int k = 0; k < 8; ++k) { a[k] = S[k] + S2[k]; b[k] = S[k] - S2[k]; }
    float aL = __shfl_up(a[7], 1), aR = __shfl_down(a[0], 1);
    float bL = __shfl_up(b[7], 1), bR = __shfl_down(b[0], 1);
    if (lane == 0)  { aL = 0.f; bL = 0.f; }   // image col -1 = 0
    if (lane == 63) { aR = 0.f; bR = 0.f; }   // image col 512 = 0
    const float rmask = ((unsigned)rm < 512u) ? 1.f : 0.f;
#pragma unroll
    for (int j = 0; j < 8; ++j) {
      float am = j ? a[j - 1] : aL;
      float ap = (j < 7) ? a[j + 1] : aR;
      float bm = j ? b[j - 1] : bL;
      float bp = (j < 7) ? b[j + 1] : bR;
      float gx = am - ap;                      // horiz [1,0,-1]
      float gy = fmaf(2.f, b[j], bm + bp);     // horiz [1,2,1]
      float m2 = fmaf(gx, gx, 1e-6f);
      m2 = fmaf(gy, gy, m2);
      mg[j] = __builtin_amdgcn_sqrtf(m2) * rmask;
    }
#pragma unroll
    for (int k = 0; k < 8; ++k) { S[k] = S2[k]; X[k] = xn[k]; }
  };

  float MM[8], MC[8], MP[8];
  magstep(row0 - 1, MM);
  magstep(row0, MC);

  float s = 0.f, ss = 0.f;
#pragma unroll
  for (int i = 0; i < 12; ++i) {
    magstep(row0 + 1 + i, MP);               // mag[r+1]
    if ((unsigned)(row0 + i) < 512u) {       // wave-uniform: real output row
      float cs[8];
#pragma unroll
      for (int k = 0; k < 8; ++k) cs[k] = (MM[k] + MP[k]) + MC[k];
      float csL = __shfl_up(cs[7], 1), csR = __shfl_down(cs[0], 1);
      if (lane == 0) csL = 0.f;
      if (lane == 63) csR = 0.f;
#pragma unroll
      for (int j = 0; j < 8; ++j) {
        float cm = j ? cs[j - 1] : csL;
        float cp = (j < 7) ? cs[j + 1] : csR;
        float t = (cm + cp) + cs[j];
        s += t;
        ss = fmaf(t, t, ss);
      }
    }
#pragma unroll
    for (int k = 0; k < 8; ++k) { MM[k] = MC[k]; MC[k] = MP[k]; }
  }

  // per-wave double reduction; fold deferred /9, /81
  double ds = (double)s * (1.0 / 9.0);
  double dss = (double)ss * (1.0 / 81.0);
  for (int off = 32; off > 0; off >>= 1) {
    ds += __shfl_down(ds, off);
    dss += __shfl_down(dss, off);
  }
  if (lane == 0) {
    size_t idx = ((size_t)bc * 44 + chunk) * 2;
    parts[idx] = ds;
    parts[idx + 1] = dss;
  }
}

// One block per batch image b: waves 0-2 reduce channel 0-2's 44 double2
// partials lane-parallel, then feats [m0,s0,m1,s1,m2,s2] -> MLP -> out.
__global__ __launch_bounds__(256) void stats_mlp(
    const double* __restrict__ parts,
    const float* __restrict__ w1, const float* __restrict__ b1,
    const float* __restrict__ w2, const float* __restrict__ b2,
    float* __restrict__ out) {
  __shared__ float feats[6];
  __shared__ float hbuf[32];
  const int tid = threadIdx.x;
  const int lane = tid & 63;
  const int w = tid >> 6;
  const int b = blockIdx.x;                  // 0..31

  if (w < 3) {
    const int bc = b * 3 + w;
    const double2* p2 = (const double2*)(parts + (size_t)bc * 88);
    double s = 0.0, ss = 0.0;
    if (lane < 44) {
      double2 v = p2[lane];
      s = v.x;
      ss = v.y;
    }
    for (int off = 32; off > 0; off >>= 1) {
      s += __shfl_down(s, off);
      ss += __shfl_down(ss, off);
    }
    if (lane == 0) {
      const double N = 262144.0;
      double mean = s / N;
      double var = (ss - s * s / N) / (N - 1.0);
      if (var < 0.0) var = 0.0;
      feats[2 * w] = (float)mean;
      feats[2 * w + 1] = (float)sqrt(var);
    }
  }
  __syncthreads();

  if (tid < 32) {
    float acc = b1[tid];
#pragma unroll
    for (int k = 0; k < 6; ++k) acc += feats[k] * w1[tid * 6 + k];
    hbuf[tid] = acc > 0.f ? acc : 0.f;
  }
  __syncthreads();

  if (tid < 64) {
    float acc = b2[tid];
#pragma unroll
    for (int j = 0; j < 32; ++j) acc += hbuf[j] * w2[tid * 32 + j];
    out[(size_t)b * 64 + tid] = acc;
  }
}

extern "C" void kernel_launch(void* const* d_in, const int* in_sizes, int n_in,
                              void* d_out, int out_size, void* d_ws, size_t ws_size,
                              hipStream_t stream) {
  const float* x = (const float*)d_in[0];
  const float* w1 = (const float*)d_in[1];
  const float* b1 = (const float*)d_in[2];
  const float* w2 = (const float*)d_in[3];
  const float* b2 = (const float*)d_in[4];
  float* out = (float*)d_out;
  double* parts = (double*)d_ws;  // 96*44*2 doubles = 67584 B

  dim3 grid(11, 96);
  sobel_pool_stats<<<grid, 256, 0, stream>>>(x, parts);
  stats_mlp<<<32, 256, 0, stream>>>(parts, w1, b1, w2, b2, out);
}